// Round 1
// baseline (328.985 us; speedup 1.0000x reference)
//
#include <hip/hip_runtime.h>
#include <math.h>

#define BATCH 4
#define HEADS 16
#define SEQ   4096
#define DIM   64
#define BHN   (BATCH*HEADS)   // 64
#define NS1   16              // pass-1 S-chunks per (b,h)
#define NS2   16              // pass-2 S-chunks per (b,h)
#define ROWS1 (SEQ/NS1)       // 256
#define ROWS2 (SEQ/NS2)       // 256

// workspace layout (float offsets)
#define WS_TAB   0                                   // S*16*2      = 131072
#define WS_MPART (WS_TAB   + SEQ*16*2)               // NS1*BH*4096 = 4194304
#define WS_KPART (WS_MPART + NS1*BHN*DIM*DIM)        // NS1*BH*64   = 65536
#define WS_MFIN  (WS_KPART + NS1*BHN*DIM)            // BH*4096     = 262144
#define WS_KFIN  (WS_MFIN  + BHN*DIM*DIM)            // BH*64       = 4096

// ---------------------------------------------------------------- cos/sin table
__global__ __launch_bounds__(256) void k_table(float* __restrict__ tab) {
    int g = blockIdx.x * 256 + threadIdx.x;      // 0 .. S*16-1
    int s = g >> 4;
    int i = g & 15;
    // inv[i] = 10000^(-i/16), computed in double like the reference (np power in f64)
    double inv = exp(-(double)i * (9.210340371976184 / 16.0));  // ln(10000)=9.2103...
    float af = (float)((double)s * inv);          // f64 product -> f32 cast (matches ref)
    float sn, cs;
    sincosf(af, &sn, &cs);
    tab[2*g]   = cs;
    tab[2*g+1] = sn;
}

// ---------------------------------------------------------------- pass 1: M = Kr^T V, ksum
__global__ __launch_bounds__(256) void k_pass1(const float* __restrict__ K,
                                               const float* __restrict__ V,
                                               const int*   __restrict__ mask,
                                               const float* __restrict__ tab,
                                               float* __restrict__ Mpart,
                                               float* __restrict__ Kpart) {
    __shared__ float Kr[64][68];     // roped K tile, padded (272B rows, 16B aligned)
    __shared__ float Vs[64][68];     // V tile
    __shared__ float ksred[8][64];   // ksum cross-thread reduction

    const int t  = threadIdx.x;
    const int bh = blockIdx.x / NS1;
    const int ns = blockIdx.x % NS1;
    const int b  = bh >> 4;                 // H = 16
    const int chunk0 = ns * ROWS1;

    const int dp     = t & 31;              // column pair 0..31  (fixed per thread)
    const int rowoff = t >> 5;              // 0..7
    const int td = t >> 4, te = t & 15;     // 4x4 output tile coords

    const size_t base = (size_t)bh * SEQ;

    float acc[4][4] = {};
    float ks0 = 0.f, ks1 = 0.f;

    for (int tile = 0; tile < ROWS1/64; ++tile) {
        const int s0 = chunk0 + tile*64;
        // ---- stage: K -> elu+1 -> mask -> (ksum) -> rope -> Kr LDS ; V -> LDS
        #pragma unroll
        for (int it = 0; it < 8; ++it) {
            const int sl   = it*8 + rowoff;
            const int srow = s0 + sl;
            float2 kv = *(const float2*)(K + (base + srow)*DIM + dp*2);
            float fm = (float)mask[b*SEQ + srow];
            float k0 = kv.x > 0.f ? kv.x + 1.f : __expf(kv.x);   // elu(x)+1
            float k1 = kv.y > 0.f ? kv.y + 1.f : __expf(kv.y);
            k0 *= fm; k1 *= fm;
            ks0 += fabsf(k0); ks1 += fabsf(k1);
            float r0 = k0, r1 = k1;
            if (dp < 16) {
                float2 cs = *(const float2*)(tab + (size_t)srow*32 + dp*2);
                r0 = k0*cs.x - k1*cs.y;
                r1 = k1*cs.x + k0*cs.y;
            }
            *(float2*)&Kr[sl][dp*2] = make_float2(r0, r1);
            float2 vv = *(const float2*)(V + (base + srow)*DIM + dp*2);
            *(float2*)&Vs[sl][dp*2] = vv;
        }
        __syncthreads();
        // ---- accumulate outer products: acc[i][j] += Kr[s][td*4+i] * V[s][te*4+j]
        #pragma unroll 4
        for (int sl = 0; sl < 64; ++sl) {
            float4 av = *(const float4*)&Kr[sl][td*4];
            float4 bv = *(const float4*)&Vs[sl][te*4];
            float a4[4] = {av.x, av.y, av.z, av.w};
            float b4[4] = {bv.x, bv.y, bv.z, bv.w};
            #pragma unroll
            for (int i = 0; i < 4; ++i)
                #pragma unroll
                for (int j = 0; j < 4; ++j)
                    acc[i][j] += a4[i] * b4[j];
        }
        __syncthreads();
    }

    // ---- ksum reduction across the 8 row-groups
    ksred[rowoff][2*dp]   = ks0;
    ksred[rowoff][2*dp+1] = ks1;
    __syncthreads();
    if (t < 64) {
        float s = 0.f;
        #pragma unroll
        for (int g = 0; g < 8; ++g) s += ksred[g][t];
        Kpart[(bh*NS1 + ns)*DIM + t] = s;
    }

    // ---- write M partial (deterministic, no atomics)
    float* pm = Mpart + (size_t)(bh*NS1 + ns) * (DIM*DIM);
    #pragma unroll
    for (int i = 0; i < 4; ++i) {
        *(float4*)(pm + (td*4 + i)*DIM + te*4) =
            make_float4(acc[i][0], acc[i][1], acc[i][2], acc[i][3]);
    }
}

// ---------------------------------------------------------------- reduce partials
__global__ __launch_bounds__(256) void k_reduce(const float* __restrict__ Mpart,
                                                const float* __restrict__ Kpart,
                                                float* __restrict__ Mfin,
                                                float* __restrict__ Kfin) {
    int g = blockIdx.x * 256 + threadIdx.x;
    if (g < BHN*DIM*DIM) {
        int bh = g >> 12, j = g & 4095;
        float s = 0.f;
        #pragma unroll
        for (int ns = 0; ns < NS1; ++ns)
            s += Mpart[(size_t)(bh*NS1 + ns)*(DIM*DIM) + j];
        Mfin[g] = s;
    } else {
        int k = g - BHN*DIM*DIM;
        if (k < BHN*DIM) {
            int bh = k >> 6, d = k & 63;
            float s = 0.f;
            #pragma unroll
            for (int ns = 0; ns < NS1; ++ns)
                s += Kpart[(bh*NS1 + ns)*DIM + d];
            Kfin[k] = s;
        }
    }
}

// ---------------------------------------------------------------- pass 2: out = (Qr M) / (Qf . ksum)
__global__ __launch_bounds__(256) void k_pass2(const float* __restrict__ Q,
                                               const float* __restrict__ tab,
                                               const float* __restrict__ Mfin,
                                               const float* __restrict__ ksum,
                                               float* __restrict__ out) {
    __shared__ float Ml[DIM*DIM];    // M row-major [d*64+e]
    __shared__ float QrT[64][68];    // Qr transposed: [d][s_local]
    __shared__ float nrm[64];
    __shared__ float ksl[64];

    const int t  = threadIdx.x;
    const int bh = blockIdx.x / NS2;
    const int ns = blockIdx.x % NS2;
    const int chunk0 = ns * ROWS2;

    // load M (16 KB) + ksum once per block
    {
        const float4* mf4 = (const float4*)(Mfin + (size_t)bh*(DIM*DIM));
        float4* ml4 = (float4*)Ml;
        #pragma unroll
        for (int it = 0; it < 4; ++it) ml4[it*256 + t] = mf4[it*256 + t];
        if (t < 64) ksl[t] = ksum[bh*DIM + t];
    }
    __syncthreads();

    const int dp     = t & 31;
    const int rowoff = t >> 5;
    const int rg = t >> 4, cg = t & 15;
    const size_t base = (size_t)bh * SEQ;

    for (int tile = 0; tile < ROWS2/64; ++tile) {
        const int s0 = chunk0 + tile*64;
        // ---- stage: Q -> elu(q*scale)+1 -> norm (row-reduce) -> rope -> QrT LDS
        #pragma unroll
        for (int it = 0; it < 8; ++it) {
            const int sl   = it*8 + rowoff;
            const int srow = s0 + sl;
            float2 qv = *(const float2*)(Q + (base + srow)*DIM + dp*2);
            float x0 = qv.x * 0.125f, x1 = qv.y * 0.125f;   // D^-0.5 = 1/8
            float q0 = x0 > 0.f ? x0 + 1.f : __expf(x0);
            float q1 = x1 > 0.f ? x1 + 1.f : __expf(x1);
            // norm partial: Qf . ksum  (reduce over the 32 lanes sharing this row)
            float np = q0*ksl[2*dp] + q1*ksl[2*dp+1];
            np += __shfl_xor(np, 1);
            np += __shfl_xor(np, 2);
            np += __shfl_xor(np, 4);
            np += __shfl_xor(np, 8);
            np += __shfl_xor(np, 16);
            if (dp == 0) nrm[sl] = np;
            float r0 = q0, r1 = q1;
            if (dp < 16) {
                float2 cs = *(const float2*)(tab + (size_t)srow*32 + dp*2);
                r0 = q0*cs.x - q1*cs.y;
                r1 = q1*cs.x + q0*cs.y;
            }
            QrT[2*dp][sl]   = r0;
            QrT[2*dp+1][sl] = r1;
        }
        __syncthreads();
        // ---- GEMM tile: out[s0+rg*4+i][cg*4+j] = sum_d QrT[d][rg*4+i]*M[d][cg*4+j]
        float acc[4][4] = {};
        #pragma unroll 8
        for (int d = 0; d < 64; ++d) {
            float4 qv4 = *(const float4*)&QrT[d][rg*4];
            float4 mv4 = *(const float4*)&Ml[d*DIM + cg*4];
            float a4[4] = {qv4.x, qv4.y, qv4.z, qv4.w};
            float b4[4] = {mv4.x, mv4.y, mv4.z, mv4.w};
            #pragma unroll
            for (int i = 0; i < 4; ++i)
                #pragma unroll
                for (int j = 0; j < 4; ++j)
                    acc[i][j] += a4[i] * b4[j];
        }
        // ---- epilogue: divide by norm, store
        #pragma unroll
        for (int i = 0; i < 4; ++i) {
            const int sl = rg*4 + i;
            float inv = 1.0f / nrm[sl];
            float4 o = make_float4(acc[i][0]*inv, acc[i][1]*inv,
                                   acc[i][2]*inv, acc[i][3]*inv);
            *(float4*)(out + (base + s0 + sl)*DIM + cg*4) = o;
        }
        __syncthreads();
    }
}

// ---------------------------------------------------------------- launch
extern "C" void kernel_launch(void* const* d_in, const int* in_sizes, int n_in,
                              void* d_out, int out_size, void* d_ws, size_t ws_size,
                              hipStream_t stream) {
    const float* Q    = (const float*)d_in[0];
    const float* K    = (const float*)d_in[1];
    const float* V    = (const float*)d_in[2];
    const int*   mask = (const int*)d_in[3];
    float* out = (float*)d_out;
    float* ws  = (float*)d_ws;

    float* tab   = ws + WS_TAB;
    float* Mpart = ws + WS_MPART;
    float* Kpart = ws + WS_KPART;
    float* Mfin  = ws + WS_MFIN;
    float* Kfin  = ws + WS_KFIN;

    k_table <<<SEQ*16/256, 256, 0, stream>>>(tab);
    k_pass1 <<<BHN*NS1,    256, 0, stream>>>(K, V, mask, tab, Mpart, Kpart);
    k_reduce<<<(BHN*DIM*DIM + BHN*DIM + 255)/256, 256, 0, stream>>>(Mpart, Kpart, Mfin, Kfin);
    k_pass2 <<<BHN*NS2,    256, 0, stream>>>(Q, tab, Mfin, Kfin, out);
}